// Round 1
// baseline (695.944 us; speedup 1.0000x reference)
//
#include <hip/hip_runtime.h>
#include <math.h>

#define B_ 256
#define T_ 256
#define I_ 2048
#define H_ 128

// ---------------------------------------------------------------------------
// Kernel 1: xp[bt][j] = sum_i x[bt][i] * W_ih[j][i] + (b_ih[j] + b_hh[j])
// fp32, tile 64 rows x 128 cols, K-step 32, 256 threads/block, 1024 blocks.
// ---------------------------------------------------------------------------
__global__ __launch_bounds__(256) void proj_kernel(
    const float* __restrict__ x, const float* __restrict__ Wih,
    const float* __restrict__ bih, const float* __restrict__ bhh,
    float* __restrict__ xp)
{
    __shared__ __align__(16) float xs[64 * 32];     // [r][k] linear
    __shared__ __align__(16) float wst[32 * 132];   // [k][j], row pad 132 (16B-aligned rows)

    const int tid = threadIdx.x;
    const int tc  = tid & 31;        // col group: cols 4*tc .. 4*tc+3
    const int tr  = tid >> 5;        // row group: rows 8*tr .. 8*tr+7
    const long row0 = (long)blockIdx.x * 64;

    float acc[8][4];
    #pragma unroll
    for (int r = 0; r < 8; ++r)
        acc[r][0] = acc[r][1] = acc[r][2] = acc[r][3] = 0.f;

    for (int kk = 0; kk < I_; kk += 32) {
        __syncthreads();   // protect previous iteration's LDS reads
        // stage x tile: 64 rows x 32 k  (coalesced global, conflict-free LDS)
        #pragma unroll
        for (int it = 0; it < 8; ++it) {
            int l = tid + it * 256;
            int r = l >> 5, c = l & 31;
            xs[r * 32 + c] = x[(row0 + r) * I_ + kk + c];
        }
        // stage W tile transposed: wst[k][j] = W_ih[j][kk+k]
        #pragma unroll
        for (int it = 0; it < 16; ++it) {
            int l = tid + it * 256;
            int j = l >> 5, c = l & 31;
            wst[c * 132 + j] = Wih[(long)j * I_ + kk + c];
        }
        __syncthreads();

        #pragma unroll
        for (int k = 0; k < 32; ++k) {
            const float4 wv = *reinterpret_cast<const float4*>(&wst[k * 132 + tc * 4]);
            #pragma unroll
            for (int r = 0; r < 8; ++r) {
                float xv = xs[(tr * 8 + r) * 32 + k];   // broadcast read (uniform per wave-pair)
                acc[r][0] += xv * wv.x;
                acc[r][1] += xv * wv.y;
                acc[r][2] += xv * wv.z;
                acc[r][3] += xv * wv.w;
            }
        }
    }

    // bias = b_ih + b_hh
    float4 bv;
    {
        const float4 b1 = *reinterpret_cast<const float4*>(&bih[tc * 4]);
        const float4 b2 = *reinterpret_cast<const float4*>(&bhh[tc * 4]);
        bv.x = b1.x + b2.x; bv.y = b1.y + b2.y;
        bv.z = b1.z + b2.z; bv.w = b1.w + b2.w;
    }
    #pragma unroll
    for (int r = 0; r < 8; ++r) {
        float4 o;
        o.x = acc[r][0] + bv.x; o.y = acc[r][1] + bv.y;
        o.z = acc[r][2] + bv.z; o.w = acc[r][3] + bv.w;
        *reinterpret_cast<float4*>(&xp[(row0 + tr * 8 + r) * H_ + tc * 4]) = o;
    }
}

// ---------------------------------------------------------------------------
// Kernel 2: per-batch-row recurrence h = tanh(xp_t + h @ W_hh^T), then
// out[b] = dot(h_T, W_fc) + b_fc.  One block per batch row, 256 threads:
// thread (j = tid&127, g = tid>>7) holds W_hh[j][64g .. 64g+63] in VGPRs.
// ---------------------------------------------------------------------------
__global__ __launch_bounds__(256) void scan_kernel(
    const float* __restrict__ xp, const float* __restrict__ Whh,
    const float* __restrict__ Wfc, const float* __restrict__ bfc,
    float* __restrict__ out)
{
    __shared__ __align__(16) float hcur[H_];
    __shared__ __align__(16) float part[2][H_];

    const int tid = threadIdx.x;
    const int j = tid & 127;
    const int g = tid >> 7;
    const int b = blockIdx.x;

    // W_hh row-chunk into registers (one-time, L2-served)
    float Wreg[64];
    {
        const float4* wp = reinterpret_cast<const float4*>(&Whh[(long)j * H_ + g * 64]);
        #pragma unroll
        for (int q = 0; q < 16; ++q) {
            float4 w = wp[q];
            Wreg[4*q]   = w.x; Wreg[4*q+1] = w.y;
            Wreg[4*q+2] = w.z; Wreg[4*q+3] = w.w;
        }
    }
    if (g == 0) hcur[j] = 0.f;
    __syncthreads();

    const float* xprow = xp + (long)b * T_ * H_;

    for (int t = 0; t < T_; ++t) {
        float xpv = 0.f;
        if (g == 0) xpv = xprow[t * H_ + j];   // issued early, consumed after k-loop

        float a0 = 0.f, a1 = 0.f, a2 = 0.f, a3 = 0.f;
        const float4* h4 = reinterpret_cast<const float4*>(&hcur[g * 64]);
        #pragma unroll
        for (int q = 0; q < 16; ++q) {
            float4 hh = h4[q];                 // uniform-address LDS read -> broadcast
            a0 += hh.x * Wreg[4*q];
            a1 += hh.y * Wreg[4*q+1];
            a2 += hh.z * Wreg[4*q+2];
            a3 += hh.w * Wreg[4*q+3];
        }
        part[g][j] = (a0 + a1) + (a2 + a3);
        __syncthreads();
        if (g == 0) {
            float pre = part[0][j] + part[1][j] + xpv;
            hcur[j] = tanhf(pre);
        }
        __syncthreads();
    }

    // final FC: out[b] = dot(h, W_fc) + b_fc
    if (g == 0) {
        float v = hcur[j] * Wfc[j];
        #pragma unroll
        for (int off = 32; off > 0; off >>= 1) v += __shfl_down(v, off);
        if ((j & 63) == 0) part[0][j >> 6] = v;
    }
    __syncthreads();
    if (tid == 0) out[b] = part[0][0] + part[0][1] + bfc[0];
}

// ---------------------------------------------------------------------------
extern "C" void kernel_launch(void* const* d_in, const int* in_sizes, int n_in,
                              void* d_out, int out_size, void* d_ws, size_t ws_size,
                              hipStream_t stream)
{
    const float* x   = (const float*)d_in[0];
    const float* Wih = (const float*)d_in[1];
    const float* Whh = (const float*)d_in[2];
    const float* bih = (const float*)d_in[3];
    const float* bhh = (const float*)d_in[4];
    const float* Wfc = (const float*)d_in[5];
    const float* bfc = (const float*)d_in[6];
    float* out = (float*)d_out;
    float* xp  = (float*)d_ws;   // 65536 * 128 floats = 32 MB scratch

    proj_kernel<<<dim3((B_ * T_) / 64), dim3(256), 0, stream>>>(x, Wih, bih, bhh, xp);
    scan_kernel<<<dim3(B_), dim3(256), 0, stream>>>(xp, Whh, Wfc, bfc, out);
}

// Round 2
// 311.287 us; speedup vs baseline: 2.2357x; 2.2357x over previous
//
#include <hip/hip_runtime.h>
#include <hip/hip_bf16.h>
#include <math.h>

#define B_ 256
#define T_ 256
#define I_ 2048
#define H_ 128

typedef __attribute__((ext_vector_type(8))) short bf16x8;
typedef __attribute__((ext_vector_type(4))) float f32x4;

static __device__ inline short f2bf(float f) {
    __hip_bfloat16 h = __float2bfloat16(f);
    return *reinterpret_cast<short*>(&h);
}

// ---------------------------------------------------------------------------
// Kernel 1 (bf16 MFMA): xp[bt][j] = sum_i x[bt][i]*W_ih[j][i] + (b_ih+b_hh)[j]
// Tile 128x128, BK=32, 4 waves (2x2 of 64x64), 16x16x32 bf16 MFMA.
// x is fp32 in HBM -> reg-stage + convert -> bf16 LDS (rows padded to 40
// shorts = 80 B so frag ds_read_b128 is ~2-way = free).
// ---------------------------------------------------------------------------
#define BM 128
#define BK 32
#define LDSROW 40   // 32 bf16 + 8 pad; 80 B row stride (16B-aligned)

__global__ __launch_bounds__(256) void proj_mfma(
    const float* __restrict__ x, const float* __restrict__ Wih,
    const float* __restrict__ bih, const float* __restrict__ bhh,
    float* __restrict__ xp)
{
    __shared__ __align__(16) short As[BM * LDSROW];
    __shared__ __align__(16) short Bs[H_ * LDSROW];

    const int tid  = threadIdx.x;
    const int lane = tid & 63;
    const int wid  = tid >> 6;
    const int wr   = wid >> 1;      // M half (0/1)
    const int wc   = wid & 1;       // N half (0/1)
    const long row0 = (long)blockIdx.x * BM;

    // staging coords: each thread loads float4 chunks at (srow + 32*it, skc)
    const int srow = tid >> 3;      // 0..31
    const int skc  = tid & 7;       // float4 chunk within 32-k tile

    f32x4 acc[4][4];
    #pragma unroll
    for (int m = 0; m < 4; ++m)
        #pragma unroll
        for (int n = 0; n < 4; ++n)
            acc[m][n] = (f32x4){0.f, 0.f, 0.f, 0.f};

    // prologue: load K-tile 0 into regs
    float4 ra[4], rb[4];
    #pragma unroll
    for (int it = 0; it < 4; ++it) {
        const int r = srow + it * 32;
        ra[it] = *reinterpret_cast<const float4*>(&x[(row0 + r) * I_ + skc * 4]);
        rb[it] = *reinterpret_cast<const float4*>(&Wih[(long)r * I_ + skc * 4]);
    }

    const int fr = lane & 15;       // fragment row within 16
    const int fq = lane >> 4;       // k-chunk 0..3

    for (int kk = 0; kk < I_; kk += BK) {
        __syncthreads();            // previous compute done with LDS
        // regs -> LDS (convert to bf16)
        #pragma unroll
        for (int it = 0; it < 4; ++it) {
            const int r = srow + it * 32;
            short4 a4, b4;
            a4.x = f2bf(ra[it].x); a4.y = f2bf(ra[it].y);
            a4.z = f2bf(ra[it].z); a4.w = f2bf(ra[it].w);
            b4.x = f2bf(rb[it].x); b4.y = f2bf(rb[it].y);
            b4.z = f2bf(rb[it].z); b4.w = f2bf(rb[it].w);
            *reinterpret_cast<short4*>(&As[r * LDSROW + skc * 4]) = a4;
            *reinterpret_cast<short4*>(&Bs[r * LDSROW + skc * 4]) = b4;
        }
        __syncthreads();
        // prefetch next K-tile into regs (overlaps with MFMA below)
        if (kk + BK < I_) {
            #pragma unroll
            for (int it = 0; it < 4; ++it) {
                const int r = srow + it * 32;
                ra[it] = *reinterpret_cast<const float4*>(
                    &x[(row0 + r) * I_ + kk + BK + skc * 4]);
                rb[it] = *reinterpret_cast<const float4*>(
                    &Wih[(long)r * I_ + kk + BK + skc * 4]);
            }
        }
        // fragments: 8 contiguous bf16 at row (l&15), k-chunk (l>>4)*8
        bf16x8 af[4], bfr[4];
        #pragma unroll
        for (int f = 0; f < 4; ++f) {
            af[f]  = *reinterpret_cast<const bf16x8*>(
                &As[(wr * 64 + f * 16 + fr) * LDSROW + fq * 8]);
            bfr[f] = *reinterpret_cast<const bf16x8*>(
                &Bs[(wc * 64 + f * 16 + fr) * LDSROW + fq * 8]);
        }
        #pragma unroll
        for (int m = 0; m < 4; ++m)
            #pragma unroll
            for (int n = 0; n < 4; ++n)
                acc[m][n] = __builtin_amdgcn_mfma_f32_16x16x32_bf16(
                    af[m], bfr[n], acc[m][n], 0, 0, 0);
    }

    // epilogue: bias + store (C layout: row=(lane>>4)*4+j, col=lane&15)
    #pragma unroll
    for (int n = 0; n < 4; ++n) {
        const int col = wc * 64 + n * 16 + fr;
        const float bn = bih[col] + bhh[col];
        #pragma unroll
        for (int m = 0; m < 4; ++m) {
            const long rbase = row0 + wr * 64 + m * 16 + fq * 4;
            #pragma unroll
            for (int j = 0; j < 4; ++j)
                xp[(rbase + j) * H_ + col] = acc[m][n][j] + bn;
        }
    }
}

// ---------------------------------------------------------------------------
// Kernel 2: per-batch-row recurrence h = tanh(xp_t + h @ W_hh^T).
// 256 blocks x 256 threads (4 waves). Wave w owns j in [32w, 32w+32);
// lane l: j = 32w + (l&31), k-half g = l>>5. W_hh[j][64g..+63] in VGPRs.
// Partial k-halves exchanged via shfl_xor(32) (intra-wave, no LDS, no
// barrier); h double-buffered in LDS -> ONE __syncthreads per step.
// ---------------------------------------------------------------------------
__global__ __launch_bounds__(256) void scan_kernel(
    const float* __restrict__ xp, const float* __restrict__ Whh,
    const float* __restrict__ Wfc, const float* __restrict__ bfc,
    float* __restrict__ out)
{
    __shared__ __align__(16) float hbuf[2][H_];

    const int tid  = threadIdx.x;
    const int lane = tid & 63;
    const int w    = tid >> 6;
    const int j    = w * 32 + (lane & 31);
    const int g    = lane >> 5;
    const int b    = blockIdx.x;

    // W_hh row-chunk into registers (L2-served; shared by all 256 blocks)
    float Wreg[64];
    {
        const float4* wp = reinterpret_cast<const float4*>(&Whh[(long)j * H_ + g * 64]);
        #pragma unroll
        for (int q = 0; q < 16; ++q) {
            const float4 wv = wp[q];
            Wreg[4*q]   = wv.x; Wreg[4*q+1] = wv.y;
            Wreg[4*q+2] = wv.z; Wreg[4*q+3] = wv.w;
        }
    }
    if (tid < H_) hbuf[0][tid] = 0.f;
    __syncthreads();

    const float* xprow = xp + (long)b * T_ * H_;

    for (int t = 0; t < T_; ++t) {
        const float xpv = xprow[t * H_ + j];   // issued early; consumed post k-loop
        const float4* h4 = reinterpret_cast<const float4*>(&hbuf[t & 1][g * 64]);
        float a0 = 0.f, a1 = 0.f, a2 = 0.f, a3 = 0.f;
        #pragma unroll
        for (int q = 0; q < 16; ++q) {
            const float4 hh = h4[q];           // uniform-per-half-wave -> broadcast
            a0 += hh.x * Wreg[4*q];
            a1 += hh.y * Wreg[4*q+1];
            a2 += hh.z * Wreg[4*q+2];
            a3 += hh.w * Wreg[4*q+3];
        }
        float part = (a0 + a1) + (a2 + a3);
        part += __shfl_xor(part, 32);          // combine k-halves in-wave
        const float pre = part + xpv;
        // tanh(x) = 1 - 2/(e^{2x}+1)  (saturates correctly at +/-inf)
        const float e = __expf(2.f * pre);
        const float h = 1.f - 2.f / (e + 1.f);
        hbuf[(t + 1) & 1][j] = h;              // both g-lanes write same value
        __syncthreads();                       // single barrier per step
    }

    // final h is in hbuf[0] (t=255 wrote buffer (255+1)&1 = 0)
    if (w == 0) {
        float v = hbuf[0][lane] * Wfc[lane] + hbuf[0][lane + 64] * Wfc[lane + 64];
        #pragma unroll
        for (int off = 32; off > 0; off >>= 1) v += __shfl_down(v, off);
        if (lane == 0) out[b] = v + bfc[0];
    }
}

// ---------------------------------------------------------------------------
extern "C" void kernel_launch(void* const* d_in, const int* in_sizes, int n_in,
                              void* d_out, int out_size, void* d_ws, size_t ws_size,
                              hipStream_t stream)
{
    const float* x   = (const float*)d_in[0];
    const float* Wih = (const float*)d_in[1];
    const float* Whh = (const float*)d_in[2];
    const float* bih = (const float*)d_in[3];
    const float* bhh = (const float*)d_in[4];
    const float* Wfc = (const float*)d_in[5];
    const float* bfc = (const float*)d_in[6];
    float* out = (float*)d_out;
    float* xp  = (float*)d_ws;   // 65536 * 128 floats = 32 MB scratch

    proj_mfma<<<dim3((B_ * T_) / BM), dim3(256), 0, stream>>>(x, Wih, bih, bhh, xp);
    scan_kernel<<<dim3(B_), dim3(256), 0, stream>>>(xp, Whh, Wfc, bfc, out);
}

// Round 3
// 270.398 us; speedup vs baseline: 2.5738x; 1.1512x over previous
//
#include <hip/hip_runtime.h>
#include <hip/hip_bf16.h>
#include <math.h>

#define B_ 256
#define T_ 256
#define I_ 2048
#define H_ 128

typedef __attribute__((ext_vector_type(8))) short bf16x8;
typedef __attribute__((ext_vector_type(4))) float f32x4;

static __device__ inline short f2bf(float f) {
    __hip_bfloat16 h = __float2bfloat16(f);
    return *reinterpret_cast<short*>(&h);
}

// ---------------------------------------------------------------------------
// Kernel 1 (bf16 MFMA): xp[bt][j] = sum_i x[bt][i]*W_ih[j][i] + (b_ih+b_hh)[j]
// Tile 128x128, BK=32, 4 waves (2x2 of 64x64), 16x16x32 bf16 MFMA.
// LDS double-buffered (ONE barrier per K-step), global loads issued 2 tiles
// ahead into regs, fp32 -> bf16 convert during the reg->LDS stage.
// ---------------------------------------------------------------------------
#define BM 128
#define BK 32
#define LDSROW 40          // 32 bf16 + 8 pad; 80 B row stride (16B-aligned)
#define NKT (I_ / BK)      // 64 K-tiles

__global__ __launch_bounds__(256, 2) void proj_mfma(
    const float* __restrict__ x, const float* __restrict__ Wih,
    const float* __restrict__ bih, const float* __restrict__ bhh,
    float* __restrict__ xp)
{
    __shared__ __align__(16) short As[2][BM * LDSROW];   // 2 x 10 KB
    __shared__ __align__(16) short Bs[2][H_ * LDSROW];   // 2 x 10 KB

    const int tid  = threadIdx.x;
    const int lane = tid & 63;
    const int wid  = tid >> 6;
    const int wr   = wid >> 1;      // M half (0/1)
    const int wc   = wid & 1;       // N half (0/1)
    const long row0 = (long)blockIdx.x * BM;

    // staging coords: thread loads float4 at rows srow+32*it, k-chunk skc
    const int srow = tid >> 3;      // 0..31
    const int skc  = tid & 7;       // float4 chunk within 32-k tile

    const float* pA = x   + (row0 + srow) * I_ + skc * 4;
    const float* pB = Wih + (long)srow * I_ + skc * 4;
    const int ldsOff = srow * LDSROW + skc * 4;

    f32x4 acc[4][4];
    #pragma unroll
    for (int m = 0; m < 4; ++m)
        #pragma unroll
        for (int n = 0; n < 4; ++n)
            acc[m][n] = (f32x4){0.f, 0.f, 0.f, 0.f};

    float4 ra[4], rb[4];
    // tile 0 -> regs
    #pragma unroll
    for (int it = 0; it < 4; ++it) {
        ra[it] = *reinterpret_cast<const float4*>(pA + (long)it * 32 * I_);
        rb[it] = *reinterpret_cast<const float4*>(pB + (long)it * 32 * I_);
    }
    // tile 0 regs -> buf0 (bf16)
    #pragma unroll
    for (int it = 0; it < 4; ++it) {
        short4 a4, b4;
        a4.x = f2bf(ra[it].x); a4.y = f2bf(ra[it].y);
        a4.z = f2bf(ra[it].z); a4.w = f2bf(ra[it].w);
        b4.x = f2bf(rb[it].x); b4.y = f2bf(rb[it].y);
        b4.z = f2bf(rb[it].z); b4.w = f2bf(rb[it].w);
        *reinterpret_cast<short4*>(&As[0][ldsOff + it * 32 * LDSROW]) = a4;
        *reinterpret_cast<short4*>(&Bs[0][ldsOff + it * 32 * LDSROW]) = b4;
    }
    // tile 1 -> regs (in flight across the barrier)
    #pragma unroll
    for (int it = 0; it < 4; ++it) {
        ra[it] = *reinterpret_cast<const float4*>(pA + (long)it * 32 * I_ + BK);
        rb[it] = *reinterpret_cast<const float4*>(pB + (long)it * 32 * I_ + BK);
    }
    __syncthreads();

    const int fr = lane & 15;
    const int fq = lane >> 4;
    const int aBase = (wr * 64 + fr) * LDSROW + fq * 8;
    const int bBase = (wc * 64 + fr) * LDSROW + fq * 8;

    int p = 0;
    for (int t = 0; t < NKT; ++t) {
        // stage tile t+1 (in regs) into buf p^1 while computing tile t on buf p
        if (t + 1 < NKT) {
            #pragma unroll
            for (int it = 0; it < 4; ++it) {
                short4 a4, b4;
                a4.x = f2bf(ra[it].x); a4.y = f2bf(ra[it].y);
                a4.z = f2bf(ra[it].z); a4.w = f2bf(ra[it].w);
                b4.x = f2bf(rb[it].x); b4.y = f2bf(rb[it].y);
                b4.z = f2bf(rb[it].z); b4.w = f2bf(rb[it].w);
                *reinterpret_cast<short4*>(&As[p ^ 1][ldsOff + it * 32 * LDSROW]) = a4;
                *reinterpret_cast<short4*>(&Bs[p ^ 1][ldsOff + it * 32 * LDSROW]) = b4;
            }
        }
        // issue tile t+2 loads (2 K-steps of latency hiding)
        if (t + 2 < NKT) {
            #pragma unroll
            for (int it = 0; it < 4; ++it) {
                ra[it] = *reinterpret_cast<const float4*>(
                    pA + (long)it * 32 * I_ + (t + 2) * BK);
                rb[it] = *reinterpret_cast<const float4*>(
                    pB + (long)it * 32 * I_ + (t + 2) * BK);
            }
        }
        // fragments + MFMA on buf p
        bf16x8 af[4], bfr[4];
        #pragma unroll
        for (int f = 0; f < 4; ++f) {
            af[f]  = *reinterpret_cast<const bf16x8*>(&As[p][aBase + f * 16 * LDSROW]);
            bfr[f] = *reinterpret_cast<const bf16x8*>(&Bs[p][bBase + f * 16 * LDSROW]);
        }
        #pragma unroll
        for (int m = 0; m < 4; ++m)
            #pragma unroll
            for (int n = 0; n < 4; ++n)
                acc[m][n] = __builtin_amdgcn_mfma_f32_16x16x32_bf16(
                    af[m], bfr[n], acc[m][n], 0, 0, 0);
        __syncthreads();   // single barrier: buf p reads done, buf p^1 writes visible
        p ^= 1;
    }

    // epilogue: bias + store (C layout: row=(lane>>4)*4+j, col=lane&15)
    #pragma unroll
    for (int n = 0; n < 4; ++n) {
        const int col = wc * 64 + n * 16 + fr;
        const float bn = bih[col] + bhh[col];
        #pragma unroll
        for (int m = 0; m < 4; ++m) {
            const long rbase = row0 + wr * 64 + m * 16 + fq * 4;
            #pragma unroll
            for (int j = 0; j < 4; ++j)
                xp[(rbase + j) * H_ + col] = acc[m][n][j] + bn;
        }
    }
}

// ---------------------------------------------------------------------------
// Kernel 2: per-batch-row recurrence h = tanh(xp_t + h @ W_hh^T).
// 256 blocks x 256 threads (4 waves). Wave w owns j in [32w, 32w+32);
// lane l: j = 32w + (l&31), k-half g = l>>5; W_hh[j][64g..+63] in VGPRs.
// k-half partials combined via shfl_xor(32); h double-buffered in LDS ->
// ONE barrier/step. xp loads prefetched 4 steps ahead (reg pipeline).
// ---------------------------------------------------------------------------
__global__ __launch_bounds__(256) void scan_kernel(
    const float* __restrict__ xp, const float* __restrict__ Whh,
    const float* __restrict__ Wfc, const float* __restrict__ bfc,
    float* __restrict__ out)
{
    __shared__ __align__(16) float hbuf[2][H_];

    const int tid  = threadIdx.x;
    const int lane = tid & 63;
    const int w    = tid >> 6;
    const int j    = w * 32 + (lane & 31);
    const int g    = lane >> 5;
    const int b    = blockIdx.x;

    float Wreg[64];
    {
        const float4* wp = reinterpret_cast<const float4*>(&Whh[(long)j * H_ + g * 64]);
        #pragma unroll
        for (int q = 0; q < 16; ++q) {
            const float4 wv = wp[q];
            Wreg[4*q]   = wv.x; Wreg[4*q+1] = wv.y;
            Wreg[4*q+2] = wv.z; Wreg[4*q+3] = wv.w;
        }
    }
    if (tid < H_) hbuf[0][tid] = 0.f;

    const float* xprow = xp + (long)b * T_ * H_ + j;
    // 4-deep prefetch pipeline: load for step t+4 issued at step t
    float xa = xprow[0 * H_];
    float xb = xprow[1 * H_];
    float xc = xprow[2 * H_];
    float xd = xprow[3 * H_];
    __syncthreads();

    auto body = [&](int t, float xpv) {
        const float4* h4 = reinterpret_cast<const float4*>(&hbuf[t & 1][g * 64]);
        float a0 = 0.f, a1 = 0.f, a2 = 0.f, a3 = 0.f;
        #pragma unroll
        for (int q = 0; q < 16; ++q) {
            const float4 hh = h4[q];            // uniform-per-half-wave -> broadcast
            a0 += hh.x * Wreg[4*q];
            a1 += hh.y * Wreg[4*q+1];
            a2 += hh.z * Wreg[4*q+2];
            a3 += hh.w * Wreg[4*q+3];
        }
        float part = (a0 + a1) + (a2 + a3);
        part += __shfl_xor(part, 32);           // combine k-halves in-wave
        const float pre = part + xpv;
        // tanh(x) = 1 - 2/(e^{2x}+1)
        const float e = __expf(2.f * pre);
        hbuf[(t + 1) & 1][j] = 1.f - 2.f / (e + 1.f);
        __syncthreads();                        // single barrier per step
    };

    for (int t = 0; t < T_; t += 4) {
        float xu;
        xu = xa; if (t + 4 < T_) xa = xprow[(long)(t + 4) * H_];
        body(t + 0, xu);
        xu = xb; if (t + 5 < T_) xb = xprow[(long)(t + 5) * H_];
        body(t + 1, xu);
        xu = xc; if (t + 6 < T_) xc = xprow[(long)(t + 6) * H_];
        body(t + 2, xu);
        xu = xd; if (t + 7 < T_) xd = xprow[(long)(t + 7) * H_];
        body(t + 3, xu);
    }

    // final h is in hbuf[0] (t=255 wrote (255+1)&1 = 0)
    if (w == 0) {
        float v = hbuf[0][lane] * Wfc[lane] + hbuf[0][lane + 64] * Wfc[lane + 64];
        #pragma unroll
        for (int off = 32; off > 0; off >>= 1) v += __shfl_down(v, off);
        if (lane == 0) out[b] = v + bfc[0];
    }
}

// ---------------------------------------------------------------------------
extern "C" void kernel_launch(void* const* d_in, const int* in_sizes, int n_in,
                              void* d_out, int out_size, void* d_ws, size_t ws_size,
                              hipStream_t stream)
{
    const float* x   = (const float*)d_in[0];
    const float* Wih = (const float*)d_in[1];
    const float* Whh = (const float*)d_in[2];
    const float* bih = (const float*)d_in[3];
    const float* bhh = (const float*)d_in[4];
    const float* Wfc = (const float*)d_in[5];
    const float* bfc = (const float*)d_in[6];
    float* out = (float*)d_out;
    float* xp  = (float*)d_ws;   // 65536 * 128 floats = 32 MB scratch

    proj_mfma<<<dim3((B_ * T_) / BM), dim3(256), 0, stream>>>(x, Wih, bih, bhh, xp);
    scan_kernel<<<dim3(B_), dim3(256), 0, stream>>>(xp, Whh, Wfc, bfc, out);
}